// Round 3
// baseline (539.269 us; speedup 1.0000x reference)
//
#include <hip/hip_runtime.h>

// ---------------------------------------------------------------------------
// Kernel A: i_x[t,b,n] = sum_k x[t,b,k] * w_in[k,n]
// Plain fp32 vector GEMM: M = T*B = 128000, K = 256, N = 256.
// Tile 128x128, 256 threads, 8x8 micro-tile per thread, BK=32.  (~112 TF)
// ---------------------------------------------------------------------------
__global__ __launch_bounds__(256) void gemm_xw(const float* __restrict__ X,
                                               const float* __restrict__ W,
                                               float* __restrict__ Y,
                                               int M) {
    __shared__ float As[32][132];
    __shared__ float Bs[32][128];

    const int tid = threadIdx.x;
    const int mb = blockIdx.x >> 1;
    const int nb = blockIdx.x & 1;
    const int m0 = mb << 7;
    const int n0 = nb << 7;
    const int tr = (tid >> 4) << 3;
    const int tc = (tid & 15) << 3;

    float acc[8][8];
#pragma unroll
    for (int i = 0; i < 8; ++i)
#pragma unroll
        for (int j = 0; j < 8; ++j) acc[i][j] = 0.f;

    for (int kb = 0; kb < 256; kb += 32) {
#pragma unroll
        for (int i = 0; i < 4; ++i) {
            int f = tid + (i << 8);
            int row = f >> 3, kq = f & 7;
            float4 a = *(const float4*)(X + (size_t)(m0 + row) * 256 + kb + (kq << 2));
            As[(kq << 2) + 0][row] = a.x;
            As[(kq << 2) + 1][row] = a.y;
            As[(kq << 2) + 2][row] = a.z;
            As[(kq << 2) + 3][row] = a.w;
            int rowb = f >> 5, cq = f & 31;
            *(float4*)&Bs[rowb][cq << 2] =
                *(const float4*)(W + (size_t)(kb + rowb) * 256 + n0 + (cq << 2));
        }
        __syncthreads();
#pragma unroll
        for (int k = 0; k < 32; ++k) {
            float a[8], b[8];
            *(float4*)&a[0] = *(const float4*)&As[k][tr];
            *(float4*)&a[4] = *(const float4*)&As[k][tr + 4];
            *(float4*)&b[0] = *(const float4*)&Bs[k][tc];
            *(float4*)&b[4] = *(const float4*)&Bs[k][tc + 4];
#pragma unroll
            for (int i = 0; i < 8; ++i)
#pragma unroll
                for (int j = 0; j < 8; ++j)
                    acc[i][j] = fmaf(a[i], b[j], acc[i][j]);
        }
        __syncthreads();
    }
#pragma unroll
    for (int i = 0; i < 8; ++i) {
        float* yp = Y + (size_t)(m0 + tr + i) * 256 + n0 + tc;
        *(float4*)yp = make_float4(acc[i][0], acc[i][1], acc[i][2], acc[i][3]);
        *(float4*)(yp + 4) = make_float4(acc[i][4], acc[i][5], acc[i][6], acc[i][7]);
    }
}

// ---------------------------------------------------------------------------
// Kernel B: sequential scan. ONE WAVE per batch sample; lane owns neurons
// 4*lane..4*lane+3. Spike masks live in SGPRs via __ballot — no LDS, no
// barriers on the recurrence. Raw v_exp_f32/v_log_f32 transcendentals.
// Sparse z@w_rec: uniform-mask scalar bit-scan + coalesced float4 row reads
// (skipped wholesale when no neuron spiked — ~75% of steps).
// i_x aliases the zs output region: read-before-overwrite per (t,b,n).
// ---------------------------------------------------------------------------
__global__ __launch_bounds__(64) void lif_seq(const float* __restrict__ ix,
                                              const float* __restrict__ wrec,
                                              const float* __restrict__ z0,
                                              const float* __restrict__ v0,
                                              const float* __restrict__ t0,
                                              float* __restrict__ zs,
                                              float* __restrict__ vs,
                                              int T, int B) {
    const int b = blockIdx.x;
    const int lane = threadIdx.x;
    const int nbase = lane << 2;
    const size_t sb = (size_t)b * 256 + nbase;
    const size_t stride = (size_t)B * 256;

    float4 v4 = *(const float4*)(v0 + sb);
    float4 t4 = *(const float4*)(t0 + sb);
    float4 z4 = *(const float4*)(z0 + sb);
    float v[4] = {v4.x, v4.y, v4.z, v4.w};
    float t[4] = {t4.x, t4.y, t4.z, t4.w};
    float z[4] = {z4.x, z4.y, z4.z, z4.w};

    unsigned long long mk[4];
#pragma unroll
    for (int c = 0; c < 4; ++c) mk[c] = __ballot(z[c] != 0.f);

    const float* ixp = ix + sb;

    auto step = [&](int ts, float4 r) {
        // ---- sparse z @ w_rec (uniform masks -> scalar branches) ----
        float ir[4] = {0.f, 0.f, 0.f, 0.f};
        if (mk[0] | mk[1] | mk[2] | mk[3]) {
#pragma unroll
            for (int c = 0; c < 4; ++c) {
                unsigned long long mm = mk[c];
                while (mm) {
                    int j = __builtin_ctzll(mm);
                    mm &= mm - 1;
                    const float4 w =
                        *(const float4*)(wrec + ((size_t)((j << 2) + c) << 8) + nbase);
                    ir[0] += w.x; ir[1] += w.y; ir[2] += w.z; ir[3] += w.w;
                }
            }
        }

        float rr[4] = {r.x, r.y, r.z, r.w};
        float nzv[4];
#pragma unroll
        for (int c = 0; c < 4; ++c) {
            float i_in = rr[c] + ir[c];
            float h = (i_in != 0.f) ? 1.f : 0.f;
            float nt = t[c] + (1.f - h);
            float nv = (z[c] != 0.f) ? 0.f : v[c];          // reset on spike
            nv = fmaxf(nv, -1.f);                           // exact clamp at -1
            float cap = __builtin_amdgcn_exp2f(fabsf(nv)) - 1.f;   // A=B=C=1
            float arg = fminf(h * (nt + 1.f), cap);                // DT=1
            float L = __builtin_amdgcn_logf((1e-5f + arg) + 1.f);  // log2
            float sgn = (nv > 0.f) ? 1.f : ((nv < 0.f) ? -1.f : 0.f);
            nv = fmaf(-sgn, L, nv);                         // exact: sgn in {-1,0,1}
            nv = nv + i_in;
            nt = nt * (1.f - h);
            float nz = ((nv - 0.5f) > 0.f) ? 1.f : 0.f;     // spike fwd, THR=0.5
            v[c] = nv;
            t[c] = nt;
            z[c] = nz;
            nzv[c] = nz;
        }
#pragma unroll
        for (int c = 0; c < 4; ++c) mk[c] = __ballot(nzv[c] != 0.f);

        size_t o = (size_t)ts * stride + sb;
        *(float4*)(zs + o) = make_float4(z[0], z[1], z[2], z[3]);  // overwrites ix[ts] after use
        *(float4*)(vs + o) = make_float4(v[0], v[1], v[2], v[3]);
    };

    // 8-deep register prefetch of the i_x stream, static indices only
    float4 buf[8];
#pragma unroll
    for (int u = 0; u < 8; ++u) buf[u] = *(const float4*)(ixp + (size_t)u * stride);

    for (int tb = 0; tb < T; tb += 8) {
#pragma unroll
        for (int u = 0; u < 8; ++u) {
            step(tb + u, buf[u]);
            int tn = tb + u + 8;
            tn = (tn < T) ? tn : (T - 1);    // clamped dummy loads at tail
            buf[u] = *(const float4*)(ixp + (size_t)tn * stride);
        }
    }
}

extern "C" void kernel_launch(void* const* d_in, const int* in_sizes, int n_in,
                              void* d_out, int out_size, void* d_ws, size_t ws_size,
                              hipStream_t stream) {
    const float* x    = (const float*)d_in[0];
    const float* z0   = (const float*)d_in[1];
    const float* v0   = (const float*)d_in[2];
    const float* t0   = (const float*)d_in[3];
    const float* w_in = (const float*)d_in[4];
    const float* wrec = (const float*)d_in[5];

    const int n_rec = 256;
    const int B = in_sizes[1] / n_rec;          // 128
    const int nin = in_sizes[4] / n_rec;        // 256
    const int T = in_sizes[0] / (B * nin);      // 1000
    const int M = T * B;                        // 128000

    float* zs = (float*)d_out;
    float* vs = zs + (size_t)T * B * n_rec;
    float* ixbuf = zs;  // stage x@w_in into the zs region (read-before-write in lif_seq)

    gemm_xw<<<dim3((M / 128) * 2), dim3(256), 0, stream>>>(x, w_in, ixbuf, M);
    lif_seq<<<dim3(B), dim3(64), 0, stream>>>(ixbuf, wrec, z0, v0, t0, zs, vs, T, B);
}